// Round 6
// baseline (977.492 us; speedup 1.0000x reference)
//
#include <hip/hip_runtime.h>

// ---------------- problem constants ----------------
constexpr int BB = 4, TT = 1024, DD = 512, HH = 8, HDIM = 64;
constexpr int FFD = 2048, NLAYER = 2, MM = 512, SS = 1536;
constexpr float LN_EPS = 1e-5f;
constexpr float SCALE = 0.04419417382415922f; // 1/sqrt(512)

typedef unsigned short u16;
typedef __attribute__((ext_vector_type(8))) short bf16x8;
typedef __attribute__((ext_vector_type(4))) float f32x4;

__device__ __forceinline__ float b2f(u16 u) {
  union { unsigned int i; float f; } c; c.i = ((unsigned int)u) << 16; return c.f;
}
__device__ __forceinline__ u16 f2b(float f) {
  unsigned int x = __builtin_bit_cast(unsigned int, f);
  x += 0x7fffu + ((x >> 16) & 1u);   // RNE (finite values only)
  return (u16)(x >> 16);
}

// ---------------- canonical input buffer offsets (elements) ----------------
constexpr int OFF_X    = 0;          // 2,097,152
constexpr int OFF_MEMS = 2097152;    // 3,145,728
constexpr int OFF_UB   = 5242880;    // 512
constexpr int OFF_VB   = 5243392;    // 512
constexpr int OFF_QKVW = 5243904;    // 1,572,864 (786,432 per layer)
constexpr int OFF_POSW = 6816768;    // 524,288 (262,144 per layer)
constexpr int OFF_OUTW = 7341056;    // 524,288
constexpr int OFF_L1W  = 7865344;    // 2,097,152 (1,048,576 per layer)
constexpr int OFF_L1B  = 9962496;    // 4,096 (2,048 per layer)
constexpr int OFF_L2W  = 9966592;    // 2,097,152
constexpr int OFF_L2B  = 12063744;   // 1,024 (512 per layer)
constexpr int OFF_LN1S = 12064768;
constexpr int OFF_LN1B = 12065792;
constexpr int OFF_LN2S = 12066816;
constexpr int OFF_LN2B = 12067840;
constexpr int TOT_IN   = 12068864;   // = 47,144 * 256

// ---------------- dtype probe: bf16 data has no huge-exponent u16 patterns ----------------
__global__ void txl_probe(const u16* __restrict__ xr, int* __restrict__ flag) {
  int lane = threadIdx.x;   // 64 threads
  int cnt = 0;
  for (int k = 0; k < 8; ++k) {
    u16 u = xr[lane * 8 + k];
    int e = (u >> 7) & 0xFF;
    if (e >= 0xC0) ++cnt;   // |bf16| > 2^65 — never in real activations
  }
  for (int o = 32; o; o >>= 1) cnt += __shfl_xor(cnt, o);
  if (lane == 0) *flag = (cnt >= 32) ? 1 : 0;   // 1 => inputs are f32
}

// ---------------- convert all float inputs to canonical bf16 buffer ----------------
__global__ __launch_bounds__(256) void txl_convert(
    const void* x, const void* mems, const void* ub, const void* vb,
    const void* qkvw, const void* posw, const void* outw,
    const void* l1w, const void* l1b, const void* l2w, const void* l2b,
    const void* ln1s, const void* ln1b, const void* ln2s, const void* ln2b,
    u16* __restrict__ dst, const int* __restrict__ flag) {
  int idx = blockIdx.x * 256 + threadIdx.x;
  if (idx >= TOT_IN) return;
  const void* p; int local;
  if      (idx < OFF_MEMS) { p = x;    local = idx; }
  else if (idx < OFF_UB)   { p = mems; local = idx - OFF_MEMS; }
  else if (idx < OFF_VB)   { p = ub;   local = idx - OFF_UB; }
  else if (idx < OFF_QKVW) { p = vb;   local = idx - OFF_VB; }
  else if (idx < OFF_POSW) { p = qkvw; local = idx - OFF_QKVW; }
  else if (idx < OFF_OUTW) { p = posw; local = idx - OFF_POSW; }
  else if (idx < OFF_L1W)  { p = outw; local = idx - OFF_OUTW; }
  else if (idx < OFF_L1B)  { p = l1w;  local = idx - OFF_L1W; }
  else if (idx < OFF_L2W)  { p = l1b;  local = idx - OFF_L1B; }
  else if (idx < OFF_L2B)  { p = l2w;  local = idx - OFF_L2W; }
  else if (idx < OFF_LN1S) { p = l2b;  local = idx - OFF_L2B; }
  else if (idx < OFF_LN1B) { p = ln1s; local = idx - OFF_LN1S; }
  else if (idx < OFF_LN2S) { p = ln1b; local = idx - OFF_LN1B; }
  else if (idx < OFF_LN2B) { p = ln2s; local = idx - OFF_LN2S; }
  else                     { p = ln2b; local = idx - OFF_LN2B; }
  dst[idx] = (*flag) ? f2b(((const float*)p)[local]) : ((const u16*)p)[local];
}

// ---------------- GEMM: C[M,N](f32) = A[M,K](bf16) * B[N,K](bf16)^T ----------------
__global__ __launch_bounds__(256) void txl_gemm(const u16* __restrict__ A,
                                                const u16* __restrict__ B,
                                                float* __restrict__ C,
                                                int M, int N, int K) {
  __shared__ __align__(16) u16 As[128][40];
  __shared__ __align__(16) u16 Bs[128][40];
  const int tid = threadIdx.x;
  const int wave = tid >> 6, lane = tid & 63;
  const int wm = (wave & 1) * 64, wn = (wave >> 1) * 64;
  const int m0 = blockIdx.x * 128, n0 = blockIdx.y * 128;
  const int L15 = lane & 15, quad = lane >> 4;
  f32x4 acc[4][4] = {};
  for (int k0 = 0; k0 < K; k0 += 32) {
    for (int c = 0; c < 2; ++c) {
      int idx = tid + c * 256;
      int row = idx >> 2, q = idx & 3;
      *reinterpret_cast<uint4*>(&As[row][q * 8]) =
          *reinterpret_cast<const uint4*>(&A[(size_t)(m0 + row) * K + k0 + q * 8]);
      *reinterpret_cast<uint4*>(&Bs[row][q * 8]) =
          *reinterpret_cast<const uint4*>(&B[(size_t)(n0 + row) * K + k0 + q * 8]);
    }
    __syncthreads();
    bf16x8 af[4], bfr[4];
    for (int t = 0; t < 4; ++t)
      af[t] = *reinterpret_cast<const bf16x8*>(&As[wm + t * 16 + L15][quad * 8]);
    for (int t = 0; t < 4; ++t)
      bfr[t] = *reinterpret_cast<const bf16x8*>(&Bs[wn + t * 16 + L15][quad * 8]);
    for (int tm = 0; tm < 4; ++tm)
      for (int tn = 0; tn < 4; ++tn)
        acc[tm][tn] = __builtin_amdgcn_mfma_f32_16x16x32_bf16(af[tm], bfr[tn], acc[tm][tn], 0, 0, 0);
    __syncthreads();
  }
  for (int tm = 0; tm < 4; ++tm)
    for (int tn = 0; tn < 4; ++tn)
      for (int r = 0; r < 4; ++r) {
        int row = m0 + wm + tm * 16 + quad * 4 + r;
        int col = n0 + wn + tn * 16 + L15;
        C[(size_t)row * N + col] = acc[tm][tn][r];
      }
}

// ---------------- sinusoid positional encoding (positions are S-1..0) ----------------
__global__ void txl_pe(u16* __restrict__ pe) {
  int idx = blockIdx.x * 256 + threadIdx.x;    // SS*256
  if (idx >= SS * 256) return;
  int p = idx >> 8, m = idx & 255;
  float posf = (float)(SS - 1 - p);
  float div = expf((float)(2 * m) * (-9.210340371976184f / 512.0f));
  float a = posf * div;
  pe[(size_t)p * DD + 2 * m] = f2b(sinf(a));
  pe[(size_t)p * DD + 2 * m + 1] = f2b(cosf(a));
}

// ---------------- [B,T,D] -> [T,B,D] (bf16 + f32 residual copy) ----------------
__global__ void txl_transpose_in(const u16* __restrict__ x, u16* __restrict__ cur_bf,
                                 float* __restrict__ cur_f) {
  int idx = blockIdx.x * 256 + threadIdx.x;    // BB*TT*DD
  if (idx >= BB * TT * DD) return;
  int b = idx >> 19, t = (idx >> 9) & 1023, d = idx & 511;
  u16 v = x[idx];
  size_t o = ((size_t)t * BB + b) * DD + d;
  cur_bf[o] = v; cur_f[o] = b2f(v);
}

// ---------------- dual-dtype output stores ----------------
__global__ void txl_store_mem(const u16* __restrict__ src, void* __restrict__ outv,
                              int off, const int* __restrict__ flag) {
  int idx = blockIdx.x * 256 + threadIdx.x;   // 1,048,576
  if (idx >= MM * BB * DD) return;
  u16 v = src[idx];
  if (*flag) ((float*)outv)[off + idx] = b2f(v);
  else       ((u16*)outv)[off + idx] = v;
}

__global__ void txl_store_final(const u16* __restrict__ cur_bf, void* __restrict__ outv,
                                const int* __restrict__ flag) {
  int idx = blockIdx.x * 256 + threadIdx.x;
  if (idx >= BB * TT * DD) return;
  int b = idx >> 19, t = (idx >> 9) & 1023, d = idx & 511;
  u16 v = cur_bf[((size_t)t * BB + b) * DD + d];
  if (*flag) ((float*)outv)[idx] = b2f(v);
  else       ((u16*)outv)[idx] = v;
}

// ---------------- qkv scatter ----------------
__global__ __launch_bounds__(256) void txl_qkv_scatter(
    const float* __restrict__ C, const u16* __restrict__ ub, const u16* __restrict__ vb,
    u16* __restrict__ qu, u16* __restrict__ qv, u16* __restrict__ kb, u16* __restrict__ vT) {
  size_t idx = (size_t)blockIdx.x * 256 + threadIdx.x;
  if (idx >= (size_t)SS * BB * 1536) return;
  int e = (int)(idx % 1536);
  int row = (int)(idx / 1536);
  int s = row >> 2, b = row & 3;
  float val = C[idx];
  if (e < 512) {
    if (s >= MM) {
      int i = s - MM, n = e >> 6, d = e & 63;
      size_t o = ((size_t)(b * HH + n) * TT + i) * HDIM + d;
      qu[o] = f2b(val + b2f(ub[e]));
      qv[o] = f2b(val + b2f(vb[e]));
    }
  } else if (e < 1024) {
    int e2 = e - 512, n = e2 >> 6, d = e2 & 63;
    kb[((size_t)(b * HH + n) * SS + s) * HDIM + d] = f2b(val);
  } else {
    int e2 = e - 1024, n = e2 >> 6, d = e2 & 63;
    vT[((size_t)(b * HH + n) * HDIM + d) * SS + s] = f2b(val);
  }
}

// ---------------- r scatter ----------------
__global__ void txl_r_scatter(const float* __restrict__ C, u16* __restrict__ rb) {
  int idx = blockIdx.x * 256 + threadIdx.x;    // SS*DD
  if (idx >= SS * DD) return;
  int p = idx >> 9, e = idx & 511;
  int n = e >> 6, d = e & 63;
  rb[((size_t)n * SS + p) * HDIM + d] = f2b(C[idx]);
}

// ---------------- flash attention v4: balanced tile pairs + 4-way K-split ----------------
// grid (32, H, B), 512 threads (8 waves). Block bx owns Q-tiles {bx, 63-bx}
// (work per block is constant). Wave w: tile_sel = w&1, kh = w>>1 (K quarter).
// No-max softmax (scores tiny); partials merged via 2-round LDS tree.
__global__ __launch_bounds__(512, 8) void txl_attn4(
    const u16* __restrict__ qu, const u16* __restrict__ qv, const u16* __restrict__ kbuf,
    const u16* __restrict__ vT, const u16* __restrict__ rbuf, u16* __restrict__ ctx) {
  __shared__ __align__(16) u16 pstage[8][16][40];   // 10,240 B
  __shared__ float mrg[2][2][64][20];                // 20,480 B (slot, tile, lane, 16 O + 4 l)
  const int b = blockIdx.z, n = blockIdx.y;
  const int tid = threadIdx.x, wave = tid >> 6, lane = tid & 63;
  const int tile_sel = wave & 1, kh = wave >> 1;
  const int L15 = lane & 15, quad = lane >> 4;
  const int tile = tile_sel ? (63 - (int)blockIdx.x) : (int)blockIdx.x;
  const int i0 = tile * 16;
  const int bh = b * HH + n;

  const u16* quB = qu + ((size_t)bh * TT + i0) * HDIM;
  const u16* qvB = qv + ((size_t)bh * TT + i0) * HDIM;
  bf16x8 aqu[2], aqv[2];
  for (int c = 0; c < 2; ++c) {
    aqu[c] = *reinterpret_cast<const bf16x8*>(&quB[(size_t)L15 * HDIM + c * 32 + quad * 8]);
    aqv[c] = *reinterpret_cast<const bf16x8*>(&qvB[(size_t)L15 * HDIM + c * 32 + quad * 8]);
  }
  const u16* kB = kbuf + (size_t)bh * SS * HDIM;
  const u16* rB = rbuf + (size_t)n * SS * HDIM;
  const u16* vB = vT + (size_t)bh * HDIM * SS;
  u16* ps = &pstage[wave][0][0];

  float l_lane[4] = {0.f, 0.f, 0.f, 0.f};
  f32x4 Oacc[4] = {};

  const int kb0 = 1008 - i0;
  const int jcEnd = (i0 + 559) >> 5;          // chunks covering all j <= i0+15+MM
  const int jcBeg = (kh * jcEnd) >> 2;
  const int jcLim = ((kh + 1) * jcEnd) >> 2;

  auto posTile = [&](int base) -> f32x4 {     // C-layout: [ii][base+L15]
    f32x4 t = {};
    if (base < SS) {
      bf16x8 br0 = *reinterpret_cast<const bf16x8*>(&rB[(size_t)(base + L15) * HDIM + quad * 8]);
      bf16x8 br1 = *reinterpret_cast<const bf16x8*>(&rB[(size_t)(base + L15) * HDIM + 32 + quad * 8]);
      t = __builtin_amdgcn_mfma_f32_16x16x32_bf16(aqv[0], br0, t, 0, 0, 0);
      t = __builtin_amdgcn_mfma_f32_16x16x32_bf16(aqv[1], br1, t, 0, 0, 0);
    }
    return t;
  };

  f32x4 pT0 = posTile(kb0 + jcBeg * 32);
  for (int jc = jcBeg; jc < jcLim; ++jc) {
    const int kbc = kb0 + jc * 32;
    f32x4 pT1 = posTile(kbc + 16);
    f32x4 pT2 = posTile(kbc + 32);

    // QK for both 16-col subtiles
    f32x4 s4[2];
    for (int s = 0; s < 2; ++s) {
      int j0 = jc * 32 + s * 16;
      bf16x8 bk0 = *reinterpret_cast<const bf16x8*>(&kB[(size_t)(j0 + L15) * HDIM + quad * 8]);
      bf16x8 bk1 = *reinterpret_cast<const bf16x8*>(&kB[(size_t)(j0 + L15) * HDIM + 32 + quad * 8]);
      f32x4 c4 = {};
      c4 = __builtin_amdgcn_mfma_f32_16x16x32_bf16(aqu[0], bk0, c4, 0, 0, 0);
      c4 = __builtin_amdgcn_mfma_f32_16x16x32_bf16(aqu[1], bk1, c4, 0, 0, 0);
      s4[s] = c4;
    }

    // shifted pos add + mask + exp (no max shift); per-lane denominator accum
    for (int r = 0; r < 4; ++r) {
      int ii = quad * 4 + r;
      int i = i0 + ii;
      int c = 15 + L15 - ii;                       // [0,30]
      int srcLane = (quad << 4) | (c & 15);
      float a0 = __shfl(pT0[r], srcLane);
      float a1 = __shfl(pT1[r], srcLane);
      float b1 = __shfl(pT2[r], srcLane);
      float sv0 = s4[0][r] + ((c < 16) ? a0 : a1);
      float sv1 = s4[1][r] + ((c < 16) ? a1 : b1);
      int j0 = jc * 32;
      sv0 = (j0 + L15 <= i + MM) ? sv0 : -3e38f;
      sv1 = (j0 + 16 + L15 <= i + MM) ? sv1 : -3e38f;
      float e0 = __expf(sv0 * SCALE);              // masked -> exp(-inf) = 0
      float e1 = __expf(sv1 * SCALE);
      l_lane[r] += e0 + e1;
      int row = ii * 40;
      ps[row + L15] = f2b(e0);
      ps[row + 16 + L15] = f2b(e1);
    }
    bf16x8 ap = *reinterpret_cast<const bf16x8*>(&ps[L15 * 40 + quad * 8]);

    // PV: K=32, 4 d-tiles
    for (int tn = 0; tn < 4; ++tn) {
      bf16x8 bv = *reinterpret_cast<const bf16x8*>(
          &vB[(size_t)(tn * 16 + L15) * SS + jc * 32 + quad * 8]);
      Oacc[tn] = __builtin_amdgcn_mfma_f32_16x16x32_bf16(ap, bv, Oacc[tn], 0, 0, 0);
    }
    pT0 = pT2;
  }

  // ---- 2-round merge tree across kh (plain adds; no max to reconcile) ----
  // round 1: kh1 -> slot0, kh3 -> slot1
  if (kh & 1) {
    float* m = &mrg[kh >> 1][tile_sel][lane][0];
    for (int tn = 0; tn < 4; ++tn)
      for (int r = 0; r < 4; ++r) m[tn * 4 + r] = Oacc[tn][r];
    for (int r = 0; r < 4; ++r) m[16 + r] = l_lane[r];
  }
  __syncthreads();
  if (!(kh & 1)) {           // kh0 += slot0, kh2 += slot1
    const float* m = &mrg[kh >> 1][tile_sel][lane][0];
    for (int tn = 0; tn < 4; ++tn)
      for (int r = 0; r < 4; ++r) Oacc[tn][r] += m[tn * 4 + r];
    for (int r = 0; r < 4; ++r) l_lane[r] += m[16 + r];
  }
  if (kh == 2) {             // kh2 writes merged (kh2+kh3) to slot1
    float* m = &mrg[1][tile_sel][lane][0];
    for (int tn = 0; tn < 4; ++tn)
      for (int r = 0; r < 4; ++r) m[tn * 4 + r] = Oacc[tn][r];
    for (int r = 0; r < 4; ++r) m[16 + r] = l_lane[r];
  }
  __syncthreads();
  if (kh == 0) {             // kh0 += slot1 -> full sum; store
    const float* m = &mrg[1][tile_sel][lane][0];
    for (int tn = 0; tn < 4; ++tn)
      for (int r = 0; r < 4; ++r) Oacc[tn][r] += m[tn * 4 + r];
    float inv[4];
    for (int r = 0; r < 4; ++r) {
      float s = l_lane[r] + m[16 + r];
      for (int o = 1; o < 16; o <<= 1) s += __shfl_xor(s, o);
      inv[r] = 1.f / s;
    }
    for (int tn = 0; tn < 4; ++tn)
      for (int r = 0; r < 4; ++r) {
        int ii = quad * 4 + r;
        ctx[((size_t)(i0 + ii) * BB + b) * DD + n * HDIM + tn * 16 + L15] =
            f2b(Oacc[tn][r] * inv[r]);
      }
  }
}

// ---------------- bias + relu -> bf16 ----------------
__global__ void txl_bias_relu(const float* __restrict__ C, const u16* __restrict__ bias,
                              u16* __restrict__ out) {
  size_t idx = (size_t)blockIdx.x * 256 + threadIdx.x;
  if (idx >= (size_t)TT * BB * FFD) return;
  int f = (int)(idx & 2047);
  float v = C[idx] + b2f(bias[f]);
  out[idx] = f2b(fmaxf(v, 0.f));
}

// ---------------- LayerNorm ----------------
__global__ __launch_bounds__(256) void txl_ln(
    const float* __restrict__ gout, const u16* __restrict__ bias,
    const float* __restrict__ resid, const u16* __restrict__ gam, const u16* __restrict__ bet,
    u16* __restrict__ ybf, float* __restrict__ yf) {
  const int row = blockIdx.x, tid = threadIdx.x;
  const int lane = tid & 63, wave = tid >> 6;
  __shared__ float red[4];
  size_t base = (size_t)row * DD;
  float x0 = gout[base + tid] + resid[base + tid];
  float x1 = gout[base + tid + 256] + resid[base + tid + 256];
  if (bias) { x0 += b2f(bias[tid]); x1 += b2f(bias[tid + 256]); }
  float s = x0 + x1;
  for (int o = 32; o; o >>= 1) s += __shfl_xor(s, o);
  if (lane == 0) red[wave] = s;
  __syncthreads();
  float mean = (red[0] + red[1] + red[2] + red[3]) * (1.f / DD);
  __syncthreads();
  float d0 = x0 - mean, d1 = x1 - mean;
  float q = d0 * d0 + d1 * d1;
  for (int o = 32; o; o >>= 1) q += __shfl_xor(q, o);
  if (lane == 0) red[wave] = q;
  __syncthreads();
  float var = (red[0] + red[1] + red[2] + red[3]) * (1.f / DD);
  float rstd = rsqrtf(var + LN_EPS);
  float y0 = d0 * rstd * b2f(gam[tid]) + b2f(bet[tid]);
  float y1 = d1 * rstd * b2f(gam[tid + 256]) + b2f(bet[tid + 256]);
  ybf[base + tid] = f2b(y0);
  ybf[base + tid + 256] = f2b(y1);
  yf[base + tid] = y0;
  yf[base + tid + 256] = y1;
}

// ---------------- workspace layout (bytes) ----------------
constexpr size_t WS_CUR_F  = 0;
constexpr size_t WS_CAT    = 8388608;
constexpr size_t WS_CBUF   = 14680064;
constexpr size_t WS_QU     = 52428800;
constexpr size_t WS_QV     = 56623104;
constexpr size_t WS_K      = 60817408;
constexpr size_t WS_VT     = 67108864;
constexpr size_t WS_R      = 73400320;
constexpr size_t WS_PE     = 74973184;
constexpr size_t WS_CTX    = 76546048;
constexpr size_t WS_HBF    = 80740352;
constexpr size_t WS_HF     = 84934656;
constexpr size_t WS_FF1    = 93323264;
constexpr size_t WS_CURBF  = 110100480;
constexpr size_t WS_CIN    = 114294784;   // bf16 [12,068,864] = 24,137,728 B
constexpr size_t WS_FLAG   = 138432512;   // int
constexpr size_t WS_TOTAL  = 138432576;

extern "C" void kernel_launch(void* const* d_in, const int* in_sizes, int n_in,
                              void* d_out, int out_size, void* d_ws, size_t ws_size,
                              hipStream_t stream) {
  (void)in_sizes; (void)n_in;

  if (ws_size < WS_TOTAL) {  // fail cleanly
    hipMemsetAsync(d_out, 0, (size_t)out_size * 2, stream);
    return;
  }
  char* ws = (char*)d_ws;
  float* cur_f  = (float*)(ws + WS_CUR_F);
  u16*   cat    = (u16*)(ws + WS_CAT);
  float* Cbuf   = (float*)(ws + WS_CBUF);
  u16*   qu     = (u16*)(ws + WS_QU);
  u16*   qv     = (u16*)(ws + WS_QV);
  u16*   kb     = (u16*)(ws + WS_K);
  u16*   vT     = (u16*)(ws + WS_VT);
  u16*   rb     = (u16*)(ws + WS_R);
  u16*   pe     = (u16*)(ws + WS_PE);
  u16*   ctx    = (u16*)(ws + WS_CTX);
  u16*   hbf    = (u16*)(ws + WS_HBF);
  float* hf     = (float*)(ws + WS_HF);
  u16*   ff1    = (u16*)(ws + WS_FF1);
  u16*   cur_bf = (u16*)(ws + WS_CURBF);
  u16*   cin    = (u16*)(ws + WS_CIN);
  int*   flag   = (int*)(ws + WS_FLAG);

  // dtype probe + canonicalize all float inputs to bf16
  txl_probe<<<1, 64, 0, stream>>>((const u16*)d_in[0], flag);
  txl_convert<<<47144, 256, 0, stream>>>(
      d_in[0], d_in[3], d_in[4], d_in[5], d_in[6], d_in[7], d_in[8],
      d_in[9], d_in[10], d_in[11], d_in[12], d_in[13], d_in[14], d_in[15], d_in[16],
      cin, flag);

  const u16* ub     = cin + OFF_UB;
  const u16* vb     = cin + OFF_VB;

  txl_pe<<<SS, 256, 0, stream>>>(pe);
  txl_transpose_in<<<8192, 256, 0, stream>>>(cin + OFF_X, cur_bf, cur_f);
  // new_mems[0] = xs rows 512..1023
  txl_store_mem<<<4096, 256, 0, stream>>>(cur_bf + 1048576, d_out, 2097152, flag);

  for (int l = 0; l < NLAYER; ++l) {
    // cat = [mems[l]; cur]
    hipMemcpyAsync(cat, cin + OFF_MEMS + (size_t)l * 1048576, 2097152,
                   hipMemcpyDeviceToDevice, stream);
    hipMemcpyAsync(cat + 1048576, cur_bf, 4194304, hipMemcpyDeviceToDevice, stream);
    // qkv
    txl_gemm<<<dim3(48, 12), 256, 0, stream>>>(cat, cin + OFF_QKVW + (size_t)l * 786432,
                                               Cbuf, 6144, 1536, 512);
    txl_qkv_scatter<<<36864, 256, 0, stream>>>(Cbuf, ub, vb, qu, qv, kb, vT);
    // r = pe @ pos_w^T
    txl_gemm<<<dim3(12, 4), 256, 0, stream>>>(pe, cin + OFF_POSW + (size_t)l * 262144,
                                              Cbuf, 1536, 512, 512);
    txl_r_scatter<<<3072, 256, 0, stream>>>(Cbuf, rb);
    // attention (flash, balanced pairs, 4-way K-split)
    txl_attn4<<<dim3(32, 8, 4), 512, 0, stream>>>(qu, qv, kb, vT, rb, ctx);
    // out projection
    txl_gemm<<<dim3(32, 4), 256, 0, stream>>>(ctx, cin + OFF_OUTW + (size_t)l * 262144,
                                              Cbuf, 4096, 512, 512);
    txl_ln<<<4096, 256, 0, stream>>>(Cbuf, nullptr, cur_f,
                                     cin + OFF_LN1S + l * 512, cin + OFF_LN1B + l * 512, hbf, hf);
    // FFN
    txl_gemm<<<dim3(32, 16), 256, 0, stream>>>(hbf, cin + OFF_L1W + (size_t)l * 1048576,
                                               Cbuf, 4096, 2048, 512);
    txl_bias_relu<<<32768, 256, 0, stream>>>(Cbuf, cin + OFF_L1B + l * 2048, ff1);
    txl_gemm<<<dim3(32, 4), 256, 0, stream>>>(ff1, cin + OFF_L2W + (size_t)l * 1048576,
                                              Cbuf, 4096, 512, 2048);
    txl_ln<<<4096, 256, 0, stream>>>(Cbuf, cin + OFF_L2B + l * 512, hf,
                                     cin + OFF_LN2S + l * 512, cin + OFF_LN2B + l * 512,
                                     cur_bf, cur_f);
    // new_mems[l+1]
    txl_store_mem<<<4096, 256, 0, stream>>>(cur_bf + 1048576, d_out,
                                            2097152 + (l + 1) * 1048576, flag);
  }
  // final = swapaxes(out, 0, 1)
  txl_store_final<<<8192, 256, 0, stream>>>(cur_bf, d_out, flag);
}

// Round 7
// 712.270 us; speedup vs baseline: 1.3724x; 1.3724x over previous
//
#include <hip/hip_runtime.h>

// ---------------- problem constants ----------------
constexpr int BB = 4, TT = 1024, DD = 512, HH = 8, HDIM = 64;
constexpr int FFD = 2048, NLAYER = 2, MM = 512, SS = 1536;
constexpr float LN_EPS = 1e-5f;
constexpr float SCALE = 0.04419417382415922f; // 1/sqrt(512)

typedef unsigned short u16;
typedef __attribute__((ext_vector_type(8))) short bf16x8;
typedef __attribute__((ext_vector_type(4))) float f32x4;

__device__ __forceinline__ float b2f(u16 u) {
  union { unsigned int i; float f; } c; c.i = ((unsigned int)u) << 16; return c.f;
}
__device__ __forceinline__ u16 f2b(float f) {
  unsigned int x = __builtin_bit_cast(unsigned int, f);
  x += 0x7fffu + ((x >> 16) & 1u);   // RNE (finite values only)
  return (u16)(x >> 16);
}

// ---------------- canonical input buffer offsets (elements) ----------------
constexpr int OFF_X    = 0;          // 2,097,152
constexpr int OFF_MEMS = 2097152;    // 3,145,728
constexpr int OFF_UB   = 5242880;    // 512
constexpr int OFF_VB   = 5243392;    // 512
constexpr int OFF_QKVW = 5243904;    // 1,572,864 (786,432 per layer)
constexpr int OFF_POSW = 6816768;    // 524,288 (262,144 per layer)
constexpr int OFF_OUTW = 7341056;    // 524,288
constexpr int OFF_L1W  = 7865344;    // 2,097,152 (1,048,576 per layer)
constexpr int OFF_L1B  = 9962496;    // 4,096 (2,048 per layer)
constexpr int OFF_L2W  = 9966592;    // 2,097,152
constexpr int OFF_L2B  = 12063744;   // 1,024 (512 per layer)
constexpr int OFF_LN1S = 12064768;
constexpr int OFF_LN1B = 12065792;
constexpr int OFF_LN2S = 12066816;
constexpr int OFF_LN2B = 12067840;
constexpr int TOT_IN   = 12068864;   // = 47,144 * 256

// ---------------- dtype probe: bf16 data has no huge-exponent u16 patterns ----------------
__global__ void txl_probe(const u16* __restrict__ xr, int* __restrict__ flag) {
  int lane = threadIdx.x;   // 64 threads
  int cnt = 0;
  for (int k = 0; k < 8; ++k) {
    u16 u = xr[lane * 8 + k];
    int e = (u >> 7) & 0xFF;
    if (e >= 0xC0) ++cnt;   // |bf16| > 2^65 — never in real activations
  }
  for (int o = 32; o; o >>= 1) cnt += __shfl_xor(cnt, o);
  if (lane == 0) *flag = (cnt >= 32) ? 1 : 0;   // 1 => inputs are f32
}

// ---------------- convert all float inputs to canonical bf16 buffer ----------------
__global__ __launch_bounds__(256) void txl_convert(
    const void* x, const void* mems, const void* ub, const void* vb,
    const void* qkvw, const void* posw, const void* outw,
    const void* l1w, const void* l1b, const void* l2w, const void* l2b,
    const void* ln1s, const void* ln1b, const void* ln2s, const void* ln2b,
    u16* __restrict__ dst, const int* __restrict__ flag) {
  int idx = blockIdx.x * 256 + threadIdx.x;
  if (idx >= TOT_IN) return;
  const void* p; int local;
  if      (idx < OFF_MEMS) { p = x;    local = idx; }
  else if (idx < OFF_UB)   { p = mems; local = idx - OFF_MEMS; }
  else if (idx < OFF_VB)   { p = ub;   local = idx - OFF_UB; }
  else if (idx < OFF_QKVW) { p = vb;   local = idx - OFF_VB; }
  else if (idx < OFF_POSW) { p = qkvw; local = idx - OFF_QKVW; }
  else if (idx < OFF_OUTW) { p = posw; local = idx - OFF_POSW; }
  else if (idx < OFF_L1W)  { p = outw; local = idx - OFF_OUTW; }
  else if (idx < OFF_L1B)  { p = l1w;  local = idx - OFF_L1W; }
  else if (idx < OFF_L2W)  { p = l1b;  local = idx - OFF_L1B; }
  else if (idx < OFF_L2B)  { p = l2w;  local = idx - OFF_L2W; }
  else if (idx < OFF_LN1S) { p = l2b;  local = idx - OFF_L2B; }
  else if (idx < OFF_LN1B) { p = ln1s; local = idx - OFF_LN1S; }
  else if (idx < OFF_LN2S) { p = ln1b; local = idx - OFF_LN1B; }
  else if (idx < OFF_LN2B) { p = ln2s; local = idx - OFF_LN2S; }
  else                     { p = ln2b; local = idx - OFF_LN2B; }
  dst[idx] = (*flag) ? f2b(((const float*)p)[local]) : ((const u16*)p)[local];
}

// ---------------- GEMM: C[M,N](f32) = A[M,K](bf16) * B[N,K](bf16)^T ----------------
__global__ __launch_bounds__(256) void txl_gemm(const u16* __restrict__ A,
                                                const u16* __restrict__ B,
                                                float* __restrict__ C,
                                                int M, int N, int K) {
  __shared__ __align__(16) u16 As[128][40];
  __shared__ __align__(16) u16 Bs[128][40];
  const int tid = threadIdx.x;
  const int wave = tid >> 6, lane = tid & 63;
  const int wm = (wave & 1) * 64, wn = (wave >> 1) * 64;
  const int m0 = blockIdx.x * 128, n0 = blockIdx.y * 128;
  const int L15 = lane & 15, quad = lane >> 4;
  f32x4 acc[4][4] = {};
  for (int k0 = 0; k0 < K; k0 += 32) {
    for (int c = 0; c < 2; ++c) {
      int idx = tid + c * 256;
      int row = idx >> 2, q = idx & 3;
      *reinterpret_cast<uint4*>(&As[row][q * 8]) =
          *reinterpret_cast<const uint4*>(&A[(size_t)(m0 + row) * K + k0 + q * 8]);
      *reinterpret_cast<uint4*>(&Bs[row][q * 8]) =
          *reinterpret_cast<const uint4*>(&B[(size_t)(n0 + row) * K + k0 + q * 8]);
    }
    __syncthreads();
    bf16x8 af[4], bfr[4];
    for (int t = 0; t < 4; ++t)
      af[t] = *reinterpret_cast<const bf16x8*>(&As[wm + t * 16 + L15][quad * 8]);
    for (int t = 0; t < 4; ++t)
      bfr[t] = *reinterpret_cast<const bf16x8*>(&Bs[wn + t * 16 + L15][quad * 8]);
    for (int tm = 0; tm < 4; ++tm)
      for (int tn = 0; tn < 4; ++tn)
        acc[tm][tn] = __builtin_amdgcn_mfma_f32_16x16x32_bf16(af[tm], bfr[tn], acc[tm][tn], 0, 0, 0);
    __syncthreads();
  }
  for (int tm = 0; tm < 4; ++tm)
    for (int tn = 0; tn < 4; ++tn)
      for (int r = 0; r < 4; ++r) {
        int row = m0 + wm + tm * 16 + quad * 4 + r;
        int col = n0 + wn + tn * 16 + L15;
        C[(size_t)row * N + col] = acc[tm][tn][r];
      }
}

// ---------------- sinusoid positional encoding (positions are S-1..0) ----------------
__global__ void txl_pe(u16* __restrict__ pe) {
  int idx = blockIdx.x * 256 + threadIdx.x;    // SS*256
  if (idx >= SS * 256) return;
  int p = idx >> 8, m = idx & 255;
  float posf = (float)(SS - 1 - p);
  float div = expf((float)(2 * m) * (-9.210340371976184f / 512.0f));
  float a = posf * div;
  pe[(size_t)p * DD + 2 * m] = f2b(sinf(a));
  pe[(size_t)p * DD + 2 * m + 1] = f2b(cosf(a));
}

// ---------------- [B,T,D] -> [T,B,D] (bf16 + f32 residual copy) ----------------
__global__ void txl_transpose_in(const u16* __restrict__ x, u16* __restrict__ cur_bf,
                                 float* __restrict__ cur_f) {
  int idx = blockIdx.x * 256 + threadIdx.x;    // BB*TT*DD
  if (idx >= BB * TT * DD) return;
  int b = idx >> 19, t = (idx >> 9) & 1023, d = idx & 511;
  u16 v = x[idx];
  size_t o = ((size_t)t * BB + b) * DD + d;
  cur_bf[o] = v; cur_f[o] = b2f(v);
}

// ---------------- dual-dtype output stores ----------------
__global__ void txl_store_mem(const u16* __restrict__ src, void* __restrict__ outv,
                              int off, const int* __restrict__ flag) {
  int idx = blockIdx.x * 256 + threadIdx.x;   // 1,048,576
  if (idx >= MM * BB * DD) return;
  u16 v = src[idx];
  if (*flag) ((float*)outv)[off + idx] = b2f(v);
  else       ((u16*)outv)[off + idx] = v;
}

__global__ void txl_store_final(const u16* __restrict__ cur_bf, void* __restrict__ outv,
                                const int* __restrict__ flag) {
  int idx = blockIdx.x * 256 + threadIdx.x;
  if (idx >= BB * TT * DD) return;
  int b = idx >> 19, t = (idx >> 9) & 1023, d = idx & 511;
  u16 v = cur_bf[((size_t)t * BB + b) * DD + d];
  if (*flag) ((float*)outv)[idx] = b2f(v);
  else       ((u16*)outv)[idx] = v;
}

// ---------------- qkv scatter ----------------
__global__ __launch_bounds__(256) void txl_qkv_scatter(
    const float* __restrict__ C, const u16* __restrict__ ub, const u16* __restrict__ vb,
    u16* __restrict__ qu, u16* __restrict__ qv, u16* __restrict__ kb, u16* __restrict__ vT) {
  size_t idx = (size_t)blockIdx.x * 256 + threadIdx.x;
  if (idx >= (size_t)SS * BB * 1536) return;
  int e = (int)(idx % 1536);
  int row = (int)(idx / 1536);
  int s = row >> 2, b = row & 3;
  float val = C[idx];
  if (e < 512) {
    if (s >= MM) {
      int i = s - MM, n = e >> 6, d = e & 63;
      size_t o = ((size_t)(b * HH + n) * TT + i) * HDIM + d;
      qu[o] = f2b(val + b2f(ub[e]));
      qv[o] = f2b(val + b2f(vb[e]));
    }
  } else if (e < 1024) {
    int e2 = e - 512, n = e2 >> 6, d = e2 & 63;
    kb[((size_t)(b * HH + n) * SS + s) * HDIM + d] = f2b(val);
  } else {
    int e2 = e - 1024, n = e2 >> 6, d = e2 & 63;
    vT[((size_t)(b * HH + n) * HDIM + d) * SS + s] = f2b(val);
  }
}

// ---------------- r scatter ----------------
__global__ void txl_r_scatter(const float* __restrict__ C, u16* __restrict__ rb) {
  int idx = blockIdx.x * 256 + threadIdx.x;    // SS*DD
  if (idx >= SS * DD) return;
  int p = idx >> 9, e = idx & 511;
  int n = e >> 6, d = e & 63;
  rb[((size_t)n * SS + p) * HDIM + d] = f2b(C[idx]);
}

// ---------------- flash attention v5: balanced pairs + 4-way K-split, no VGPR clamp ----
// grid (32, H, B), 512 threads (8 waves). Block bx owns Q-tiles {bx, 63-bx}
// (work per block is constant). Wave w: tile_sel = w&1, kh = w>>1 (K quarter).
// No-max softmax (scores tiny); partials merged via 2-round LDS tree.
// NOTE: no min-waves arg in launch_bounds — (512,8) forced VGPR=32 and spilled
// ~830 MB/dispatch to scratch (R6: FETCH 713 MB, 237 us). Body needs ~64 VGPRs.
__global__ __launch_bounds__(512) void txl_attn5(
    const u16* __restrict__ qu, const u16* __restrict__ qv, const u16* __restrict__ kbuf,
    const u16* __restrict__ vT, const u16* __restrict__ rbuf, u16* __restrict__ ctx) {
  __shared__ __align__(16) u16 pstage[8][16][40];   // 10,240 B
  __shared__ float mrg[2][2][64][20];                // 20,480 B (slot, tile, lane, 16 O + 4 l)
  const int b = blockIdx.z, n = blockIdx.y;
  const int tid = threadIdx.x, wave = tid >> 6, lane = tid & 63;
  const int tile_sel = wave & 1, kh = wave >> 1;
  const int L15 = lane & 15, quad = lane >> 4;
  const int tile = tile_sel ? (63 - (int)blockIdx.x) : (int)blockIdx.x;
  const int i0 = tile * 16;
  const int bh = b * HH + n;

  const u16* quB = qu + ((size_t)bh * TT + i0) * HDIM;
  const u16* qvB = qv + ((size_t)bh * TT + i0) * HDIM;
  bf16x8 aqu[2], aqv[2];
  for (int c = 0; c < 2; ++c) {
    aqu[c] = *reinterpret_cast<const bf16x8*>(&quB[(size_t)L15 * HDIM + c * 32 + quad * 8]);
    aqv[c] = *reinterpret_cast<const bf16x8*>(&qvB[(size_t)L15 * HDIM + c * 32 + quad * 8]);
  }
  const u16* kB = kbuf + (size_t)bh * SS * HDIM;
  const u16* rB = rbuf + (size_t)n * SS * HDIM;
  const u16* vB = vT + (size_t)bh * HDIM * SS;
  u16* ps = &pstage[wave][0][0];

  float l_lane[4] = {0.f, 0.f, 0.f, 0.f};
  f32x4 Oacc[4] = {};

  const int kb0 = 1008 - i0;
  const int jcEnd = (i0 + 559) >> 5;          // chunks covering all j <= i0+15+MM
  const int jcBeg = (kh * jcEnd) >> 2;
  const int jcLim = ((kh + 1) * jcEnd) >> 2;

  auto posTile = [&](int base) -> f32x4 {     // C-layout: [ii][base+L15]
    f32x4 t = {};
    if (base < SS) {
      bf16x8 br0 = *reinterpret_cast<const bf16x8*>(&rB[(size_t)(base + L15) * HDIM + quad * 8]);
      bf16x8 br1 = *reinterpret_cast<const bf16x8*>(&rB[(size_t)(base + L15) * HDIM + 32 + quad * 8]);
      t = __builtin_amdgcn_mfma_f32_16x16x32_bf16(aqv[0], br0, t, 0, 0, 0);
      t = __builtin_amdgcn_mfma_f32_16x16x32_bf16(aqv[1], br1, t, 0, 0, 0);
    }
    return t;
  };

  f32x4 pT0 = posTile(kb0 + jcBeg * 32);
  for (int jc = jcBeg; jc < jcLim; ++jc) {
    const int kbc = kb0 + jc * 32;
    f32x4 pT1 = posTile(kbc + 16);
    f32x4 pT2 = posTile(kbc + 32);

    // QK for both 16-col subtiles
    f32x4 s4[2];
    for (int s = 0; s < 2; ++s) {
      int j0 = jc * 32 + s * 16;
      bf16x8 bk0 = *reinterpret_cast<const bf16x8*>(&kB[(size_t)(j0 + L15) * HDIM + quad * 8]);
      bf16x8 bk1 = *reinterpret_cast<const bf16x8*>(&kB[(size_t)(j0 + L15) * HDIM + 32 + quad * 8]);
      f32x4 c4 = {};
      c4 = __builtin_amdgcn_mfma_f32_16x16x32_bf16(aqu[0], bk0, c4, 0, 0, 0);
      c4 = __builtin_amdgcn_mfma_f32_16x16x32_bf16(aqu[1], bk1, c4, 0, 0, 0);
      s4[s] = c4;
    }

    // shifted pos add + mask + exp (no max shift); per-lane denominator accum
    for (int r = 0; r < 4; ++r) {
      int ii = quad * 4 + r;
      int i = i0 + ii;
      int c = 15 + L15 - ii;                       // [0,30]
      int srcLane = (quad << 4) | (c & 15);
      float a0 = __shfl(pT0[r], srcLane);
      float a1 = __shfl(pT1[r], srcLane);
      float b1 = __shfl(pT2[r], srcLane);
      float sv0 = s4[0][r] + ((c < 16) ? a0 : a1);
      float sv1 = s4[1][r] + ((c < 16) ? a1 : b1);
      int j0 = jc * 32;
      sv0 = (j0 + L15 <= i + MM) ? sv0 : -3e38f;
      sv1 = (j0 + 16 + L15 <= i + MM) ? sv1 : -3e38f;
      float e0 = __expf(sv0 * SCALE);              // masked -> exp(-inf) = 0
      float e1 = __expf(sv1 * SCALE);
      l_lane[r] += e0 + e1;
      int row = ii * 40;
      ps[row + L15] = f2b(e0);
      ps[row + 16 + L15] = f2b(e1);
    }
    bf16x8 ap = *reinterpret_cast<const bf16x8*>(&ps[L15 * 40 + quad * 8]);

    // PV: K=32, 4 d-tiles
    for (int tn = 0; tn < 4; ++tn) {
      bf16x8 bv = *reinterpret_cast<const bf16x8*>(
          &vB[(size_t)(tn * 16 + L15) * SS + jc * 32 + quad * 8]);
      Oacc[tn] = __builtin_amdgcn_mfma_f32_16x16x32_bf16(ap, bv, Oacc[tn], 0, 0, 0);
    }
    pT0 = pT2;
  }

  // ---- 2-round merge tree across kh (plain adds; no max to reconcile) ----
  // round 1: kh1 -> slot0, kh3 -> slot1
  if (kh & 1) {
    float* m = &mrg[kh >> 1][tile_sel][lane][0];
    for (int tn = 0; tn < 4; ++tn)
      for (int r = 0; r < 4; ++r) m[tn * 4 + r] = Oacc[tn][r];
    for (int r = 0; r < 4; ++r) m[16 + r] = l_lane[r];
  }
  __syncthreads();
  if (!(kh & 1)) {           // kh0 += slot0, kh2 += slot1
    const float* m = &mrg[kh >> 1][tile_sel][lane][0];
    for (int tn = 0; tn < 4; ++tn)
      for (int r = 0; r < 4; ++r) Oacc[tn][r] += m[tn * 4 + r];
    for (int r = 0; r < 4; ++r) l_lane[r] += m[16 + r];
  }
  if (kh == 2) {             // kh2 writes merged (kh2+kh3) to slot1
    float* m = &mrg[1][tile_sel][lane][0];
    for (int tn = 0; tn < 4; ++tn)
      for (int r = 0; r < 4; ++r) m[tn * 4 + r] = Oacc[tn][r];
    for (int r = 0; r < 4; ++r) m[16 + r] = l_lane[r];
  }
  __syncthreads();
  if (kh == 0) {             // kh0 += slot1 -> full sum; store
    const float* m = &mrg[1][tile_sel][lane][0];
    for (int tn = 0; tn < 4; ++tn)
      for (int r = 0; r < 4; ++r) Oacc[tn][r] += m[tn * 4 + r];
    float inv[4];
    for (int r = 0; r < 4; ++r) {
      float s = l_lane[r] + m[16 + r];
      for (int o = 1; o < 16; o <<= 1) s += __shfl_xor(s, o);
      inv[r] = 1.f / s;
    }
    for (int tn = 0; tn < 4; ++tn)
      for (int r = 0; r < 4; ++r) {
        int ii = quad * 4 + r;
        ctx[((size_t)(i0 + ii) * BB + b) * DD + n * HDIM + tn * 16 + L15] =
            f2b(Oacc[tn][r] * inv[r]);
      }
  }
}

// ---------------- bias + relu -> bf16 ----------------
__global__ void txl_bias_relu(const float* __restrict__ C, const u16* __restrict__ bias,
                              u16* __restrict__ out) {
  size_t idx = (size_t)blockIdx.x * 256 + threadIdx.x;
  if (idx >= (size_t)TT * BB * FFD) return;
  int f = (int)(idx & 2047);
  float v = C[idx] + b2f(bias[f]);
  out[idx] = f2b(fmaxf(v, 0.f));
}

// ---------------- LayerNorm ----------------
__global__ __launch_bounds__(256) void txl_ln(
    const float* __restrict__ gout, const u16* __restrict__ bias,
    const float* __restrict__ resid, const u16* __restrict__ gam, const u16* __restrict__ bet,
    u16* __restrict__ ybf, float* __restrict__ yf) {
  const int row = blockIdx.x, tid = threadIdx.x;
  const int lane = tid & 63, wave = tid >> 6;
  __shared__ float red[4];
  size_t base = (size_t)row * DD;
  float x0 = gout[base + tid] + resid[base + tid];
  float x1 = gout[base + tid + 256] + resid[base + tid + 256];
  if (bias) { x0 += b2f(bias[tid]); x1 += b2f(bias[tid + 256]); }
  float s = x0 + x1;
  for (int o = 32; o; o >>= 1) s += __shfl_xor(s, o);
  if (lane == 0) red[wave] = s;
  __syncthreads();
  float mean = (red[0] + red[1] + red[2] + red[3]) * (1.f / DD);
  __syncthreads();
  float d0 = x0 - mean, d1 = x1 - mean;
  float q = d0 * d0 + d1 * d1;
  for (int o = 32; o; o >>= 1) q += __shfl_xor(q, o);
  if (lane == 0) red[wave] = q;
  __syncthreads();
  float var = (red[0] + red[1] + red[2] + red[3]) * (1.f / DD);
  float rstd = rsqrtf(var + LN_EPS);
  float y0 = d0 * rstd * b2f(gam[tid]) + b2f(bet[tid]);
  float y1 = d1 * rstd * b2f(gam[tid + 256]) + b2f(bet[tid + 256]);
  ybf[base + tid] = f2b(y0);
  ybf[base + tid + 256] = f2b(y1);
  yf[base + tid] = y0;
  yf[base + tid + 256] = y1;
}

// ---------------- workspace layout (bytes) ----------------
constexpr size_t WS_CUR_F  = 0;
constexpr size_t WS_CAT    = 8388608;
constexpr size_t WS_CBUF   = 14680064;
constexpr size_t WS_QU     = 52428800;
constexpr size_t WS_QV     = 56623104;
constexpr size_t WS_K      = 60817408;
constexpr size_t WS_VT     = 67108864;
constexpr size_t WS_R      = 73400320;
constexpr size_t WS_PE     = 74973184;
constexpr size_t WS_CTX    = 76546048;
constexpr size_t WS_HBF    = 80740352;
constexpr size_t WS_HF     = 84934656;
constexpr size_t WS_FF1    = 93323264;
constexpr size_t WS_CURBF  = 110100480;
constexpr size_t WS_CIN    = 114294784;   // bf16 [12,068,864] = 24,137,728 B
constexpr size_t WS_FLAG   = 138432512;   // int
constexpr size_t WS_TOTAL  = 138432576;

extern "C" void kernel_launch(void* const* d_in, const int* in_sizes, int n_in,
                              void* d_out, int out_size, void* d_ws, size_t ws_size,
                              hipStream_t stream) {
  (void)in_sizes; (void)n_in;

  if (ws_size < WS_TOTAL) {  // fail cleanly
    hipMemsetAsync(d_out, 0, (size_t)out_size * 2, stream);
    return;
  }
  char* ws = (char*)d_ws;
  float* cur_f  = (float*)(ws + WS_CUR_F);
  u16*   cat    = (u16*)(ws + WS_CAT);
  float* Cbuf   = (float*)(ws + WS_CBUF);
  u16*   qu     = (u16*)(ws + WS_QU);
  u16*   qv     = (u16*)(ws + WS_QV);
  u16*   kb     = (u16*)(ws + WS_K);
  u16*   vT     = (u16*)(ws + WS_VT);
  u16*   rb     = (u16*)(ws + WS_R);
  u16*   pe     = (u16*)(ws + WS_PE);
  u16*   ctx    = (u16*)(ws + WS_CTX);
  u16*   hbf    = (u16*)(ws + WS_HBF);
  float* hf     = (float*)(ws + WS_HF);
  u16*   ff1    = (u16*)(ws + WS_FF1);
  u16*   cur_bf = (u16*)(ws + WS_CURBF);
  u16*   cin    = (u16*)(ws + WS_CIN);
  int*   flag   = (int*)(ws + WS_FLAG);

  // dtype probe + canonicalize all float inputs to bf16
  txl_probe<<<1, 64, 0, stream>>>((const u16*)d_in[0], flag);
  txl_convert<<<47144, 256, 0, stream>>>(
      d_in[0], d_in[3], d_in[4], d_in[5], d_in[6], d_in[7], d_in[8],
      d_in[9], d_in[10], d_in[11], d_in[12], d_in[13], d_in[14], d_in[15], d_in[16],
      cin, flag);

  const u16* ub     = cin + OFF_UB;
  const u16* vb     = cin + OFF_VB;

  txl_pe<<<SS, 256, 0, stream>>>(pe);
  txl_transpose_in<<<8192, 256, 0, stream>>>(cin + OFF_X, cur_bf, cur_f);
  // new_mems[0] = xs rows 512..1023
  txl_store_mem<<<4096, 256, 0, stream>>>(cur_bf + 1048576, d_out, 2097152, flag);

  for (int l = 0; l < NLAYER; ++l) {
    // cat = [mems[l]; cur]
    hipMemcpyAsync(cat, cin + OFF_MEMS + (size_t)l * 1048576, 2097152,
                   hipMemcpyDeviceToDevice, stream);
    hipMemcpyAsync(cat + 1048576, cur_bf, 4194304, hipMemcpyDeviceToDevice, stream);
    // qkv
    txl_gemm<<<dim3(48, 12), 256, 0, stream>>>(cat, cin + OFF_QKVW + (size_t)l * 786432,
                                               Cbuf, 6144, 1536, 512);
    txl_qkv_scatter<<<36864, 256, 0, stream>>>(Cbuf, ub, vb, qu, qv, kb, vT);
    // r = pe @ pos_w^T
    txl_gemm<<<dim3(12, 4), 256, 0, stream>>>(pe, cin + OFF_POSW + (size_t)l * 262144,
                                              Cbuf, 1536, 512, 512);
    txl_r_scatter<<<3072, 256, 0, stream>>>(Cbuf, rb);
    // attention (flash, balanced pairs, 4-way K-split)
    txl_attn5<<<dim3(32, 8, 4), 512, 0, stream>>>(qu, qv, kb, vT, rb, ctx);
    // out projection
    txl_gemm<<<dim3(32, 4), 256, 0, stream>>>(ctx, cin + OFF_OUTW + (size_t)l * 262144,
                                              Cbuf, 4096, 512, 512);
    txl_ln<<<4096, 256, 0, stream>>>(Cbuf, nullptr, cur_f,
                                     cin + OFF_LN1S + l * 512, cin + OFF_LN1B + l * 512, hbf, hf);
    // FFN
    txl_gemm<<<dim3(32, 16), 256, 0, stream>>>(hbf, cin + OFF_L1W + (size_t)l * 1048576,
                                               Cbuf, 4096, 2048, 512);
    txl_bias_relu<<<32768, 256, 0, stream>>>(Cbuf, cin + OFF_L1B + l * 2048, ff1);
    txl_gemm<<<dim3(32, 4), 256, 0, stream>>>(ff1, cin + OFF_L2W + (size_t)l * 1048576,
                                              Cbuf, 4096, 512, 2048);
    txl_ln<<<4096, 256, 0, stream>>>(Cbuf, cin + OFF_L2B + l * 512, hf,
                                     cin + OFF_LN2S + l * 512, cin + OFF_LN2B + l * 512,
                                     cur_bf, cur_f);
    // new_mems[l+1]
    txl_store_mem<<<4096, 256, 0, stream>>>(cur_bf + 1048576, d_out,
                                            2097152 + (l + 1) * 1048576, flag);
  }
  // final = swapaxes(out, 0, 1)
  txl_store_final<<<8192, 256, 0, stream>>>(cur_bf, d_out, flag);
}

// Round 8
// 708.279 us; speedup vs baseline: 1.3801x; 1.0056x over previous
//
#include <hip/hip_runtime.h>

// ---------------- problem constants ----------------
constexpr int BB = 4, TT = 1024, DD = 512, HH = 8, HDIM = 64;
constexpr int FFD = 2048, NLAYER = 2, MM = 512, SS = 1536;
constexpr float LN_EPS = 1e-5f;
constexpr float SCALE = 0.04419417382415922f; // 1/sqrt(512)

typedef unsigned short u16;
typedef __attribute__((ext_vector_type(8))) short bf16x8;
typedef __attribute__((ext_vector_type(4))) float f32x4;

__device__ __forceinline__ float b2f(u16 u) {
  union { unsigned int i; float f; } c; c.i = ((unsigned int)u) << 16; return c.f;
}
__device__ __forceinline__ u16 f2b(float f) {
  unsigned int x = __builtin_bit_cast(unsigned int, f);
  x += 0x7fffu + ((x >> 16) & 1u);   // RNE (finite values only)
  return (u16)(x >> 16);
}

// ---------------- canonical input buffer offsets (elements) ----------------
constexpr int OFF_X    = 0;          // 2,097,152
constexpr int OFF_MEMS = 2097152;    // 3,145,728
constexpr int OFF_UB   = 5242880;    // 512
constexpr int OFF_VB   = 5243392;    // 512
constexpr int OFF_QKVW = 5243904;    // 1,572,864 (786,432 per layer)
constexpr int OFF_POSW = 6816768;    // 524,288 (262,144 per layer)
constexpr int OFF_OUTW = 7341056;    // 524,288
constexpr int OFF_L1W  = 7865344;    // 2,097,152 (1,048,576 per layer)
constexpr int OFF_L1B  = 9962496;    // 4,096 (2,048 per layer)
constexpr int OFF_L2W  = 9966592;    // 2,097,152
constexpr int OFF_L2B  = 12063744;   // 1,024 (512 per layer)
constexpr int OFF_LN1S = 12064768;
constexpr int OFF_LN1B = 12065792;
constexpr int OFF_LN2S = 12066816;
constexpr int OFF_LN2B = 12067840;
constexpr int TOT_IN   = 12068864;   // = 47,144 * 256

// ---------------- dtype probe: bf16 data has no huge-exponent u16 patterns ----------------
__global__ void txl_probe(const u16* __restrict__ xr, int* __restrict__ flag) {
  int lane = threadIdx.x;   // 64 threads
  int cnt = 0;
  for (int k = 0; k < 8; ++k) {
    u16 u = xr[lane * 8 + k];
    int e = (u >> 7) & 0xFF;
    if (e >= 0xC0) ++cnt;   // |bf16| > 2^65 — never in real activations
  }
  for (int o = 32; o; o >>= 1) cnt += __shfl_xor(cnt, o);
  if (lane == 0) *flag = (cnt >= 32) ? 1 : 0;   // 1 => inputs are f32
}

// ---------------- convert all float inputs to canonical bf16 buffer ----------------
__global__ __launch_bounds__(256) void txl_convert(
    const void* x, const void* mems, const void* ub, const void* vb,
    const void* qkvw, const void* posw, const void* outw,
    const void* l1w, const void* l1b, const void* l2w, const void* l2b,
    const void* ln1s, const void* ln1b, const void* ln2s, const void* ln2b,
    u16* __restrict__ dst, const int* __restrict__ flag) {
  int idx = blockIdx.x * 256 + threadIdx.x;
  if (idx >= TOT_IN) return;
  const void* p; int local;
  if      (idx < OFF_MEMS) { p = x;    local = idx; }
  else if (idx < OFF_UB)   { p = mems; local = idx - OFF_MEMS; }
  else if (idx < OFF_VB)   { p = ub;   local = idx - OFF_UB; }
  else if (idx < OFF_QKVW) { p = vb;   local = idx - OFF_VB; }
  else if (idx < OFF_POSW) { p = qkvw; local = idx - OFF_QKVW; }
  else if (idx < OFF_OUTW) { p = posw; local = idx - OFF_POSW; }
  else if (idx < OFF_L1W)  { p = outw; local = idx - OFF_OUTW; }
  else if (idx < OFF_L1B)  { p = l1w;  local = idx - OFF_L1W; }
  else if (idx < OFF_L2W)  { p = l1b;  local = idx - OFF_L1B; }
  else if (idx < OFF_L2B)  { p = l2w;  local = idx - OFF_L2W; }
  else if (idx < OFF_LN1S) { p = l2b;  local = idx - OFF_L2B; }
  else if (idx < OFF_LN1B) { p = ln1s; local = idx - OFF_LN1S; }
  else if (idx < OFF_LN2S) { p = ln1b; local = idx - OFF_LN1B; }
  else if (idx < OFF_LN2B) { p = ln2s; local = idx - OFF_LN2S; }
  else                     { p = ln2b; local = idx - OFF_LN2B; }
  dst[idx] = (*flag) ? f2b(((const float*)p)[local]) : ((const u16*)p)[local];
}

// ---------------- GEMM: C[M,N](f32) = A[M,K](bf16) * B[N,K](bf16)^T ----------------
__global__ __launch_bounds__(256) void txl_gemm(const u16* __restrict__ A,
                                                const u16* __restrict__ B,
                                                float* __restrict__ C,
                                                int M, int N, int K) {
  __shared__ __align__(16) u16 As[128][40];
  __shared__ __align__(16) u16 Bs[128][40];
  const int tid = threadIdx.x;
  const int wave = tid >> 6, lane = tid & 63;
  const int wm = (wave & 1) * 64, wn = (wave >> 1) * 64;
  const int m0 = blockIdx.x * 128, n0 = blockIdx.y * 128;
  const int L15 = lane & 15, quad = lane >> 4;
  f32x4 acc[4][4] = {};
  for (int k0 = 0; k0 < K; k0 += 32) {
    for (int c = 0; c < 2; ++c) {
      int idx = tid + c * 256;
      int row = idx >> 2, q = idx & 3;
      *reinterpret_cast<uint4*>(&As[row][q * 8]) =
          *reinterpret_cast<const uint4*>(&A[(size_t)(m0 + row) * K + k0 + q * 8]);
      *reinterpret_cast<uint4*>(&Bs[row][q * 8]) =
          *reinterpret_cast<const uint4*>(&B[(size_t)(n0 + row) * K + k0 + q * 8]);
    }
    __syncthreads();
    bf16x8 af[4], bfr[4];
    for (int t = 0; t < 4; ++t)
      af[t] = *reinterpret_cast<const bf16x8*>(&As[wm + t * 16 + L15][quad * 8]);
    for (int t = 0; t < 4; ++t)
      bfr[t] = *reinterpret_cast<const bf16x8*>(&Bs[wn + t * 16 + L15][quad * 8]);
    for (int tm = 0; tm < 4; ++tm)
      for (int tn = 0; tn < 4; ++tn)
        acc[tm][tn] = __builtin_amdgcn_mfma_f32_16x16x32_bf16(af[tm], bfr[tn], acc[tm][tn], 0, 0, 0);
    __syncthreads();
  }
  for (int tm = 0; tm < 4; ++tm)
    for (int tn = 0; tn < 4; ++tn)
      for (int r = 0; r < 4; ++r) {
        int row = m0 + wm + tm * 16 + quad * 4 + r;
        int col = n0 + wn + tn * 16 + L15;
        C[(size_t)row * N + col] = acc[tm][tn][r];
      }
}

// ---------------- sinusoid positional encoding (positions are S-1..0) ----------------
__global__ void txl_pe(u16* __restrict__ pe) {
  int idx = blockIdx.x * 256 + threadIdx.x;    // SS*256
  if (idx >= SS * 256) return;
  int p = idx >> 8, m = idx & 255;
  float posf = (float)(SS - 1 - p);
  float div = expf((float)(2 * m) * (-9.210340371976184f / 512.0f));
  float a = posf * div;
  pe[(size_t)p * DD + 2 * m] = f2b(sinf(a));
  pe[(size_t)p * DD + 2 * m + 1] = f2b(cosf(a));
}

// ---------------- [B,T,D] -> [T,B,D] (bf16 + f32 residual copy) ----------------
__global__ void txl_transpose_in(const u16* __restrict__ x, u16* __restrict__ cur_bf,
                                 float* __restrict__ cur_f) {
  int idx = blockIdx.x * 256 + threadIdx.x;    // BB*TT*DD
  if (idx >= BB * TT * DD) return;
  int b = idx >> 19, t = (idx >> 9) & 1023, d = idx & 511;
  u16 v = x[idx];
  size_t o = ((size_t)t * BB + b) * DD + d;
  cur_bf[o] = v; cur_f[o] = b2f(v);
}

// ---------------- dual-dtype output stores ----------------
__global__ void txl_store_mem(const u16* __restrict__ src, void* __restrict__ outv,
                              int off, const int* __restrict__ flag) {
  int idx = blockIdx.x * 256 + threadIdx.x;   // 1,048,576
  if (idx >= MM * BB * DD) return;
  u16 v = src[idx];
  if (*flag) ((float*)outv)[off + idx] = b2f(v);
  else       ((u16*)outv)[off + idx] = v;
}

__global__ void txl_store_final(const u16* __restrict__ cur_bf, void* __restrict__ outv,
                                const int* __restrict__ flag) {
  int idx = blockIdx.x * 256 + threadIdx.x;
  if (idx >= BB * TT * DD) return;
  int b = idx >> 19, t = (idx >> 9) & 1023, d = idx & 511;
  u16 v = cur_bf[((size_t)t * BB + b) * DD + d];
  if (*flag) ((float*)outv)[idx] = b2f(v);
  else       ((u16*)outv)[idx] = v;
}

// ---------------- qkv scatter ----------------
__global__ __launch_bounds__(256) void txl_qkv_scatter(
    const float* __restrict__ C, const u16* __restrict__ ub, const u16* __restrict__ vb,
    u16* __restrict__ qu, u16* __restrict__ qv, u16* __restrict__ kb, u16* __restrict__ vT) {
  size_t idx = (size_t)blockIdx.x * 256 + threadIdx.x;
  if (idx >= (size_t)SS * BB * 1536) return;
  int e = (int)(idx % 1536);
  int row = (int)(idx / 1536);
  int s = row >> 2, b = row & 3;
  float val = C[idx];
  if (e < 512) {
    if (s >= MM) {
      int i = s - MM, n = e >> 6, d = e & 63;
      size_t o = ((size_t)(b * HH + n) * TT + i) * HDIM + d;
      qu[o] = f2b(val + b2f(ub[e]));
      qv[o] = f2b(val + b2f(vb[e]));
    }
  } else if (e < 1024) {
    int e2 = e - 512, n = e2 >> 6, d = e2 & 63;
    kb[((size_t)(b * HH + n) * SS + s) * HDIM + d] = f2b(val);
  } else {
    int e2 = e - 1024, n = e2 >> 6, d = e2 & 63;
    vT[((size_t)(b * HH + n) * HDIM + d) * SS + s] = f2b(val);
  }
}

// ---------------- r scatter ----------------
__global__ void txl_r_scatter(const float* __restrict__ C, u16* __restrict__ rb) {
  int idx = blockIdx.x * 256 + threadIdx.x;    // SS*DD
  if (idx >= SS * DD) return;
  int p = idx >> 9, e = idx & 511;
  int n = e >> 6, d = e & 63;
  rb[((size_t)n * SS + p) * HDIM + d] = f2b(C[idx]);
}

// ---------------- flash attention v6: XCD-locality swizzle ----------------
// 1024 blocks, 512 threads (8 waves). Work remapped so all 32 blocks sharing
// one (b,h)'s K/V have linear block id = cls (mod 8) -> same XCD under
// round-robin dispatch; that group's ~600 KB of K/V/r then lives in one 4 MB
// L2 (R7 un-swizzled: FETCH 185 MB = 8x L2 replication, loads at HBM latency).
// Block owns Q-tiles {bx, 63-bx} (constant work); wave w: tile_sel=w&1,
// kh=w>>1 (K quarter). No-max softmax; 2-round LDS merge tree.
__global__ __launch_bounds__(512) void txl_attn6(
    const u16* __restrict__ qu, const u16* __restrict__ qv, const u16* __restrict__ kbuf,
    const u16* __restrict__ vT, const u16* __restrict__ rbuf, u16* __restrict__ ctx) {
  __shared__ __align__(16) u16 pstage[8][16][40];   // 10,240 B
  __shared__ float mrg[2][2][64][20];                // 20,480 B (slot, tile, lane, 16 O + 4 l)
  const int lin = blockIdx.x + 32 * (blockIdx.y + 8 * blockIdx.z);
  const int cls = lin & 7;           // presumed XCD (round-robin)
  const int jj = lin >> 3;           // 0..127
  const int grp = cls * 4 + (jj >> 5);  // 0..31: (b,h) group pinned to cls
  const int bx = jj & 31;
  const int n = grp & 7, b = grp >> 3;
  const int tid = threadIdx.x, wave = tid >> 6, lane = tid & 63;
  const int tile_sel = wave & 1, kh = wave >> 1;
  const int L15 = lane & 15, quad = lane >> 4;
  const int tile = tile_sel ? (63 - bx) : bx;
  const int i0 = tile * 16;
  const int bh = b * HH + n;

  const u16* quB = qu + ((size_t)bh * TT + i0) * HDIM;
  const u16* qvB = qv + ((size_t)bh * TT + i0) * HDIM;
  bf16x8 aqu[2], aqv[2];
  for (int c = 0; c < 2; ++c) {
    aqu[c] = *reinterpret_cast<const bf16x8*>(&quB[(size_t)L15 * HDIM + c * 32 + quad * 8]);
    aqv[c] = *reinterpret_cast<const bf16x8*>(&qvB[(size_t)L15 * HDIM + c * 32 + quad * 8]);
  }
  const u16* kB = kbuf + (size_t)bh * SS * HDIM;
  const u16* rB = rbuf + (size_t)n * SS * HDIM;
  const u16* vB = vT + (size_t)bh * HDIM * SS;
  u16* ps = &pstage[wave][0][0];

  float l_lane[4] = {0.f, 0.f, 0.f, 0.f};
  f32x4 Oacc[4] = {};

  const int kb0 = 1008 - i0;
  const int jcEnd = (i0 + 559) >> 5;          // chunks covering all j <= i0+15+MM
  const int jcBeg = (kh * jcEnd) >> 2;
  const int jcLim = ((kh + 1) * jcEnd) >> 2;

  auto posTile = [&](int base) -> f32x4 {     // C-layout: [ii][base+L15]
    f32x4 t = {};
    if (base < SS) {
      bf16x8 br0 = *reinterpret_cast<const bf16x8*>(&rB[(size_t)(base + L15) * HDIM + quad * 8]);
      bf16x8 br1 = *reinterpret_cast<const bf16x8*>(&rB[(size_t)(base + L15) * HDIM + 32 + quad * 8]);
      t = __builtin_amdgcn_mfma_f32_16x16x32_bf16(aqv[0], br0, t, 0, 0, 0);
      t = __builtin_amdgcn_mfma_f32_16x16x32_bf16(aqv[1], br1, t, 0, 0, 0);
    }
    return t;
  };

  f32x4 pT0 = posTile(kb0 + jcBeg * 32);
  for (int jc = jcBeg; jc < jcLim; ++jc) {
    const int kbc = kb0 + jc * 32;
    f32x4 pT1 = posTile(kbc + 16);
    f32x4 pT2 = posTile(kbc + 32);

    // QK for both 16-col subtiles
    f32x4 s4[2];
    for (int s = 0; s < 2; ++s) {
      int j0 = jc * 32 + s * 16;
      bf16x8 bk0 = *reinterpret_cast<const bf16x8*>(&kB[(size_t)(j0 + L15) * HDIM + quad * 8]);
      bf16x8 bk1 = *reinterpret_cast<const bf16x8*>(&kB[(size_t)(j0 + L15) * HDIM + 32 + quad * 8]);
      f32x4 c4 = {};
      c4 = __builtin_amdgcn_mfma_f32_16x16x32_bf16(aqu[0], bk0, c4, 0, 0, 0);
      c4 = __builtin_amdgcn_mfma_f32_16x16x32_bf16(aqu[1], bk1, c4, 0, 0, 0);
      s4[s] = c4;
    }

    // shifted pos add + mask + exp (no max shift); per-lane denominator accum
    for (int r = 0; r < 4; ++r) {
      int ii = quad * 4 + r;
      int i = i0 + ii;
      int c = 15 + L15 - ii;                       // [0,30]
      int srcLane = (quad << 4) | (c & 15);
      float a0 = __shfl(pT0[r], srcLane);
      float a1 = __shfl(pT1[r], srcLane);
      float b1 = __shfl(pT2[r], srcLane);
      float sv0 = s4[0][r] + ((c < 16) ? a0 : a1);
      float sv1 = s4[1][r] + ((c < 16) ? a1 : b1);
      int j0 = jc * 32;
      sv0 = (j0 + L15 <= i + MM) ? sv0 : -3e38f;
      sv1 = (j0 + 16 + L15 <= i + MM) ? sv1 : -3e38f;
      float e0 = __expf(sv0 * SCALE);              // masked -> exp(-inf) = 0
      float e1 = __expf(sv1 * SCALE);
      l_lane[r] += e0 + e1;
      int row = ii * 40;
      ps[row + L15] = f2b(e0);
      ps[row + 16 + L15] = f2b(e1);
    }
    bf16x8 ap = *reinterpret_cast<const bf16x8*>(&ps[L15 * 40 + quad * 8]);

    // PV: K=32, 4 d-tiles
    for (int tn = 0; tn < 4; ++tn) {
      bf16x8 bv = *reinterpret_cast<const bf16x8*>(
          &vB[(size_t)(tn * 16 + L15) * SS + jc * 32 + quad * 8]);
      Oacc[tn] = __builtin_amdgcn_mfma_f32_16x16x32_bf16(ap, bv, Oacc[tn], 0, 0, 0);
    }
    pT0 = pT2;
  }

  // ---- 2-round merge tree across kh (plain adds; no max to reconcile) ----
  if (kh & 1) {
    float* m = &mrg[kh >> 1][tile_sel][lane][0];
    for (int tn = 0; tn < 4; ++tn)
      for (int r = 0; r < 4; ++r) m[tn * 4 + r] = Oacc[tn][r];
    for (int r = 0; r < 4; ++r) m[16 + r] = l_lane[r];
  }
  __syncthreads();
  if (!(kh & 1)) {           // kh0 += slot0, kh2 += slot1
    const float* m = &mrg[kh >> 1][tile_sel][lane][0];
    for (int tn = 0; tn < 4; ++tn)
      for (int r = 0; r < 4; ++r) Oacc[tn][r] += m[tn * 4 + r];
    for (int r = 0; r < 4; ++r) l_lane[r] += m[16 + r];
  }
  if (kh == 2) {             // kh2 writes merged (kh2+kh3) to slot1
    float* m = &mrg[1][tile_sel][lane][0];
    for (int tn = 0; tn < 4; ++tn)
      for (int r = 0; r < 4; ++r) m[tn * 4 + r] = Oacc[tn][r];
    for (int r = 0; r < 4; ++r) m[16 + r] = l_lane[r];
  }
  __syncthreads();
  if (kh == 0) {             // kh0 += slot1 -> full sum; store
    const float* m = &mrg[1][tile_sel][lane][0];
    for (int tn = 0; tn < 4; ++tn)
      for (int r = 0; r < 4; ++r) Oacc[tn][r] += m[tn * 4 + r];
    float inv[4];
    for (int r = 0; r < 4; ++r) {
      float s = l_lane[r] + m[16 + r];
      for (int o = 1; o < 16; o <<= 1) s += __shfl_xor(s, o);
      inv[r] = 1.f / s;
    }
    for (int tn = 0; tn < 4; ++tn)
      for (int r = 0; r < 4; ++r) {
        int ii = quad * 4 + r;
        ctx[((size_t)(i0 + ii) * BB + b) * DD + n * HDIM + tn * 16 + L15] =
            f2b(Oacc[tn][r] * inv[r]);
      }
  }
}

// ---------------- bias + relu -> bf16 ----------------
__global__ void txl_bias_relu(const float* __restrict__ C, const u16* __restrict__ bias,
                              u16* __restrict__ out) {
  size_t idx = (size_t)blockIdx.x * 256 + threadIdx.x;
  if (idx >= (size_t)TT * BB * FFD) return;
  int f = (int)(idx & 2047);
  float v = C[idx] + b2f(bias[f]);
  out[idx] = f2b(fmaxf(v, 0.f));
}

// ---------------- LayerNorm ----------------
__global__ __launch_bounds__(256) void txl_ln(
    const float* __restrict__ gout, const u16* __restrict__ bias,
    const float* __restrict__ resid, const u16* __restrict__ gam, const u16* __restrict__ bet,
    u16* __restrict__ ybf, float* __restrict__ yf) {
  const int row = blockIdx.x, tid = threadIdx.x;
  const int lane = tid & 63, wave = tid >> 6;
  __shared__ float red[4];
  size_t base = (size_t)row * DD;
  float x0 = gout[base + tid] + resid[base + tid];
  float x1 = gout[base + tid + 256] + resid[base + tid + 256];
  if (bias) { x0 += b2f(bias[tid]); x1 += b2f(bias[tid + 256]); }
  float s = x0 + x1;
  for (int o = 32; o; o >>= 1) s += __shfl_xor(s, o);
  if (lane == 0) red[wave] = s;
  __syncthreads();
  float mean = (red[0] + red[1] + red[2] + red[3]) * (1.f / DD);
  __syncthreads();
  float d0 = x0 - mean, d1 = x1 - mean;
  float q = d0 * d0 + d1 * d1;
  for (int o = 32; o; o >>= 1) q += __shfl_xor(q, o);
  if (lane == 0) red[wave] = q;
  __syncthreads();
  float var = (red[0] + red[1] + red[2] + red[3]) * (1.f / DD);
  float rstd = rsqrtf(var + LN_EPS);
  float y0 = d0 * rstd * b2f(gam[tid]) + b2f(bet[tid]);
  float y1 = d1 * rstd * b2f(gam[tid + 256]) + b2f(bet[tid + 256]);
  ybf[base + tid] = f2b(y0);
  ybf[base + tid + 256] = f2b(y1);
  yf[base + tid] = y0;
  yf[base + tid + 256] = y1;
}

// ---------------- workspace layout (bytes) ----------------
constexpr size_t WS_CUR_F  = 0;
constexpr size_t WS_CAT    = 8388608;
constexpr size_t WS_CBUF   = 14680064;
constexpr size_t WS_QU     = 52428800;
constexpr size_t WS_QV     = 56623104;
constexpr size_t WS_K      = 60817408;
constexpr size_t WS_VT     = 67108864;
constexpr size_t WS_R      = 73400320;
constexpr size_t WS_PE     = 74973184;
constexpr size_t WS_CTX    = 76546048;
constexpr size_t WS_HBF    = 80740352;
constexpr size_t WS_HF     = 84934656;
constexpr size_t WS_FF1    = 93323264;
constexpr size_t WS_CURBF  = 110100480;
constexpr size_t WS_CIN    = 114294784;   // bf16 [12,068,864] = 24,137,728 B
constexpr size_t WS_FLAG   = 138432512;   // int
constexpr size_t WS_TOTAL  = 138432576;

extern "C" void kernel_launch(void* const* d_in, const int* in_sizes, int n_in,
                              void* d_out, int out_size, void* d_ws, size_t ws_size,
                              hipStream_t stream) {
  (void)in_sizes; (void)n_in;

  if (ws_size < WS_TOTAL) {  // fail cleanly
    hipMemsetAsync(d_out, 0, (size_t)out_size * 2, stream);
    return;
  }
  char* ws = (char*)d_ws;
  float* cur_f  = (float*)(ws + WS_CUR_F);
  u16*   cat    = (u16*)(ws + WS_CAT);
  float* Cbuf   = (float*)(ws + WS_CBUF);
  u16*   qu     = (u16*)(ws + WS_QU);
  u16*   qv     = (u16*)(ws + WS_QV);
  u16*   kb     = (u16*)(ws + WS_K);
  u16*   vT     = (u16*)(ws + WS_VT);
  u16*   rb     = (u16*)(ws + WS_R);
  u16*   pe     = (u16*)(ws + WS_PE);
  u16*   ctx    = (u16*)(ws + WS_CTX);
  u16*   hbf    = (u16*)(ws + WS_HBF);
  float* hf     = (float*)(ws + WS_HF);
  u16*   ff1    = (u16*)(ws + WS_FF1);
  u16*   cur_bf = (u16*)(ws + WS_CURBF);
  u16*   cin    = (u16*)(ws + WS_CIN);
  int*   flag   = (int*)(ws + WS_FLAG);

  // dtype probe + canonicalize all float inputs to bf16
  txl_probe<<<1, 64, 0, stream>>>((const u16*)d_in[0], flag);
  txl_convert<<<47144, 256, 0, stream>>>(
      d_in[0], d_in[3], d_in[4], d_in[5], d_in[6], d_in[7], d_in[8],
      d_in[9], d_in[10], d_in[11], d_in[12], d_in[13], d_in[14], d_in[15], d_in[16],
      cin, flag);

  const u16* ub     = cin + OFF_UB;
  const u16* vb     = cin + OFF_VB;

  txl_pe<<<SS, 256, 0, stream>>>(pe);
  txl_transpose_in<<<8192, 256, 0, stream>>>(cin + OFF_X, cur_bf, cur_f);
  // new_mems[0] = xs rows 512..1023
  txl_store_mem<<<4096, 256, 0, stream>>>(cur_bf + 1048576, d_out, 2097152, flag);

  for (int l = 0; l < NLAYER; ++l) {
    // cat = [mems[l]; cur]
    hipMemcpyAsync(cat, cin + OFF_MEMS + (size_t)l * 1048576, 2097152,
                   hipMemcpyDeviceToDevice, stream);
    hipMemcpyAsync(cat + 1048576, cur_bf, 4194304, hipMemcpyDeviceToDevice, stream);
    // qkv
    txl_gemm<<<dim3(48, 12), 256, 0, stream>>>(cat, cin + OFF_QKVW + (size_t)l * 786432,
                                               Cbuf, 6144, 1536, 512);
    txl_qkv_scatter<<<36864, 256, 0, stream>>>(Cbuf, ub, vb, qu, qv, kb, vT);
    // r = pe @ pos_w^T
    txl_gemm<<<dim3(12, 4), 256, 0, stream>>>(pe, cin + OFF_POSW + (size_t)l * 262144,
                                              Cbuf, 1536, 512, 512);
    txl_r_scatter<<<3072, 256, 0, stream>>>(Cbuf, rb);
    // attention (flash, XCD-swizzled, balanced pairs, 4-way K-split)
    txl_attn6<<<dim3(32, 8, 4), 512, 0, stream>>>(qu, qv, kb, vT, rb, ctx);
    // out projection
    txl_gemm<<<dim3(32, 4), 256, 0, stream>>>(ctx, cin + OFF_OUTW + (size_t)l * 262144,
                                              Cbuf, 4096, 512, 512);
    txl_ln<<<4096, 256, 0, stream>>>(Cbuf, nullptr, cur_f,
                                     cin + OFF_LN1S + l * 512, cin + OFF_LN1B + l * 512, hbf, hf);
    // FFN
    txl_gemm<<<dim3(32, 16), 256, 0, stream>>>(hbf, cin + OFF_L1W + (size_t)l * 1048576,
                                               Cbuf, 4096, 2048, 512);
    txl_bias_relu<<<32768, 256, 0, stream>>>(Cbuf, cin + OFF_L1B + l * 2048, ff1);
    txl_gemm<<<dim3(32, 4), 256, 0, stream>>>(ff1, cin + OFF_L2W + (size_t)l * 1048576,
                                              Cbuf, 4096, 512, 2048);
    txl_ln<<<4096, 256, 0, stream>>>(Cbuf, cin + OFF_L2B + l * 512, hf,
                                     cin + OFF_LN2S + l * 512, cin + OFF_LN2B + l * 512,
                                     cur_bf, cur_f);
    // new_mems[l+1]
    txl_store_mem<<<4096, 256, 0, stream>>>(cur_bf + 1048576, d_out,
                                            2097152 + (l + 1) * 1048576, flag);
  }
  // final = swapaxes(out, 0, 1)
  txl_store_final<<<8192, 256, 0, stream>>>(cur_bf, d_out, flag);
}